// Round 3
// baseline (228.865 us; speedup 1.0000x reference)
//
#include <hip/hip_runtime.h>
#include <math.h>

#define DIM 1024
#define NPAIRS 512   // DIM/2
#define NLEVELS 9    // l = 1..9 (l=0 is a no-op in the reference)

// ---------------------------------------------------------------------------
// Kernel 1: collapse the 9 butterfly levels into one complex weight per pair.
// Each level l applies z <- (a - i b) * z to z = u[2p] + i*u[2p+1], with
// (a,b) shared per block of size 2^l. Composite weight is row-independent.
// ---------------------------------------------------------------------------
__global__ void butterfly_weights_kernel(const float* __restrict__ params,
                                         float2* __restrict__ w) {
    int p = blockIdx.x * blockDim.x + threadIdx.x;
    if (p >= NPAIRS) return;
    float wr = 1.0f, wi = 0.0f;
    int off = 2 * DIM;  // first 2048 params belong to l=0, which is a no-op
#pragma unroll
    for (int l = 1; l <= NLEVELS; ++l) {
        int j = p >> (l - 1);              // block index at this level
        float a = params[off + 2 * j];
        float b = params[off + 2 * j + 1];
        // (wr + i wi) * (a - i b)
        float nr = wr * a + wi * b;
        float ni = wi * a - wr * b;
        wr = nr;
        wi = ni;
        off += 2 * (DIM >> l);
    }
    w[p] = make_float2(wr, wi);
}

// ---------------------------------------------------------------------------
// Kernel 2: ONE WAVE PER ROW. No __syncthreads, no LDS.
//
// Algebra: u = s1*x with s1 = artanh(r)/r, r = ||x||.
//          y_pair = w_pair * u_pair (complex mul)  =>
//          ||y||^2 = s1^2 * sum_p |w_p|^2 * ||x_pair||^2.
// So BOTH reduction operands (sum x^2, sum |w|^2*|x_pair|^2) come from a
// single pass over x, reduced together with interleaved __shfl_xor
// (independent chains -> latencies overlap). Then:
//          out = s1 * tanh(vn)/vn * (w (*) x),  vn = s1*sqrt(sum2).
//
// 64 lanes * 4 float4 = 1024 floats per row. x and w live in registers the
// whole time; w (4 KB) is L1-resident across all waves.
// ---------------------------------------------------------------------------
__global__ __launch_bounds__(256) void hyper_butterfly_wave_kernel(
        const float* __restrict__ x,
        const float4* __restrict__ w4,   // (wr0, wi0, wr1, wi1) per float4
        float* __restrict__ out,
        int rows) {
    const int lane = threadIdx.x & 63;
    const int wave = threadIdx.x >> 6;
    const int row = blockIdx.x * 4 + wave;
    if (row >= rows) return;

    const float4* xrow = (const float4*)(x + (size_t)row * DIM);

    float4 xv[4], wv[4];
#pragma unroll
    for (int i = 0; i < 4; ++i) {
        xv[i] = xrow[lane + 64 * i];   // coalesced: 64 lanes * 16 B
        wv[i] = w4[lane + 64 * i];
    }

    // ---- single fused pass: p1 = sum x^2, p2 = sum |w|^2 * |x_pair|^2 ----
    float p1 = 0.0f, p2 = 0.0f;
#pragma unroll
    for (int i = 0; i < 4; ++i) {
        float a0 = xv[i].x * xv[i].x + xv[i].y * xv[i].y;   // |pair0|^2
        float a1 = xv[i].z * xv[i].z + xv[i].w * xv[i].w;   // |pair1|^2
        float m0 = wv[i].x * wv[i].x + wv[i].y * wv[i].y;   // |w0|^2
        float m1 = wv[i].z * wv[i].z + wv[i].w * wv[i].w;   // |w1|^2
        p1 += a0 + a1;
        p2 += m0 * a0 + m1 * a1;
    }

    // ---- wave-level butterfly reduce, both sums interleaved ----
#pragma unroll
    for (int o = 32; o > 0; o >>= 1) {
        p1 += __shfl_xor(p1, o);
        p2 += __shfl_xor(p2, o);
    }

    // ---- scalars: log map scale s1, exp map scale s2 ----
    float r = sqrtf(p1);
    float s1 = (r > 1e-12f) ? (0.5f * logf((1.0f + r) / (1.0f - r)) / r)
                            : 1.0f;                         // artanh(r)/r
    float vn = fmaxf(s1 * sqrtf(p2), 1e-8f);                // ||y||
    float s2 = tanhf(vn) / vn;
    float s = s1 * s2;

    // ---- output: s * (w (*) x), complex mul per adjacent pair ----
    float4* orow = (float4*)(out + (size_t)row * DIM);
#pragma unroll
    for (int i = 0; i < 4; ++i) {
        float4 o4;
        o4.x = s * (wv[i].x * xv[i].x - wv[i].y * xv[i].y);
        o4.y = s * (wv[i].x * xv[i].y + wv[i].y * xv[i].x);
        o4.z = s * (wv[i].z * xv[i].z - wv[i].w * xv[i].w);
        o4.w = s * (wv[i].z * xv[i].w + wv[i].w * xv[i].z);
        orow[lane + 64 * i] = o4;
    }
}

extern "C" void kernel_launch(void* const* d_in, const int* in_sizes, int n_in,
                              void* d_out, int out_size, void* d_ws, size_t ws_size,
                              hipStream_t stream) {
    const float* x = (const float*)d_in[0];
    const float* params = (const float*)d_in[1];
    float* out = (float*)d_out;
    float2* w = (float2*)d_ws;  // 512 * 8 B = 4 KB scratch

    // in_sizes[] is in ELEMENTS (verified: /DIM passed the harness in the
    // previous session; /(DIM*sizeof(float)) dropped 3/4 of rows).
    int rows = in_sizes[0] / DIM;

    butterfly_weights_kernel<<<1, NPAIRS, 0, stream>>>(params, w);

    int blocks = (rows + 3) / 4;   // 4 waves/block, 1 row per wave
    hyper_butterfly_wave_kernel<<<blocks, 256, 0, stream>>>(
        x, (const float4*)w, out, rows);
}